// Round 1
// baseline (2797.268 us; speedup 1.0000x reference)
//
#include <hip/hip_runtime.h>

// Problem constants (match reference setup_inputs)
constexpr int B = 4, C = 16, H = 512, W = 512;
constexpr int HW = H * W;

__global__ __launch_bounds__(256) void forward_warp_kernel(
    const float* __restrict__ im0,   // [B,C,H,W]
    const float* __restrict__ flow,  // [B,H,W,2]
    float* __restrict__ out)         // [B,C,H,W], pre-zeroed
{
    int idx = blockIdx.x * blockDim.x + threadIdx.x;
    constexpr int total = B * H * W;
    if (idx >= total) return;

    int w = idx & (W - 1);
    int h = (idx >> 9) & (H - 1);   // W=512 -> shift 9
    int b = idx >> 18;              // H*W = 2^18

    float2 f = *reinterpret_cast<const float2*>(flow + (size_t)idx * 2);
    float xd = (float)w + f.x;
    float yd = (float)h + f.y;
    float xff = floorf(xd);
    float yff = floorf(yd);
    int xf = (int)xff, yf = (int)yff;
    int xc = xf + 1, yc = yf + 1;

    // reference: contribution kept only if ALL four corners in-bounds
    if (xf < 0 || yf < 0 || xc >= W || yc >= H) return;

    float ax = xd - xff;            // in [0,1)
    float ay = yd - yff;
    float wnw = (1.0f - ax) * (1.0f - ay);
    float wne = ax * (1.0f - ay);
    float wsw = (1.0f - ax) * ay;
    float wse = ax * ay;

    size_t plane0 = (size_t)b * C * HW;      // base of (b, c=0)
    size_t srcoff = plane0 + (size_t)h * W + w;
    int d00 = yf * W + xf;                   // nw corner, flat within plane

    #pragma unroll
    for (int c = 0; c < C; ++c) {
        float v = im0[srcoff + (size_t)c * HW];
        float* o = out + plane0 + (size_t)c * HW + d00;
        atomicAdd(o,         v * wnw);
        atomicAdd(o + 1,     v * wne);
        atomicAdd(o + W,     v * wsw);
        atomicAdd(o + W + 1, v * wse);
    }
}

extern "C" void kernel_launch(void* const* d_in, const int* in_sizes, int n_in,
                              void* d_out, int out_size, void* d_ws, size_t ws_size,
                              hipStream_t stream) {
    const float* im0  = (const float*)d_in[0];
    const float* flow = (const float*)d_in[1];
    float* out = (float*)d_out;

    // harness poisons d_out (0xAA) and never re-poisons between replays:
    // we must zero it ourselves every call.
    hipMemsetAsync(out, 0, (size_t)out_size * sizeof(float), stream);

    constexpr int total = B * H * W;
    constexpr int block = 256;
    constexpr int grid = (total + block - 1) / block;
    forward_warp_kernel<<<grid, block, 0, stream>>>(im0, flow, out);
}

// Round 2
// 431.584 us; speedup vs baseline: 6.4814x; 6.4814x over previous
//
#include <hip/hip_runtime.h>

constexpr int B = 4, C = 16, H = 512, W = 512;
constexpr int HW = H * W;

constexpr int T   = 64;            // output tile edge (disjoint ownership)
constexpr float FR = 47.0f;        // max |flow| component handled by tiled pass
constexpr int RAD = 48;            // scan halo (= FR+1)
constexpr int WIN = T + 2 * RAD;   // 160 source-window edge
constexpr int NCH = 4;             // channels per workgroup
constexpr int NCG = C / NCH;       // 4 channel groups

// ---------- Pass A: rare far-fliers via direct global atomics ----------
__global__ __launch_bounds__(256) void warp_far_kernel(
    const float* __restrict__ im0, const float* __restrict__ flow,
    float* __restrict__ out)
{
    int idx = blockIdx.x * 256 + threadIdx.x;
    if (idx >= B * H * W) return;
    float2 f = reinterpret_cast<const float2*>(flow)[idx];
    // tiled pass handles |fx|<=FR && |fy|<=FR; we handle the complement
    if (fabsf(f.x) <= FR && fabsf(f.y) <= FR) return;

    int w = idx & (W - 1);
    int h = (idx >> 9) & (H - 1);
    int b = idx >> 18;

    float xd = (float)w + f.x;
    float yd = (float)h + f.y;
    float xff = floorf(xd), yff = floorf(yd);
    // guard int conversion with float-domain bounds check first
    if (!(xff >= 0.0f && yff >= 0.0f && xff + 1.0f <= (float)(W - 1) &&
          yff + 1.0f <= (float)(H - 1))) return;
    int xf = (int)xff, yf = (int)yff;

    float ax = xd - xff, ay = yd - yff;
    float wnw = (1.0f - ax) * (1.0f - ay);
    float wne = ax * (1.0f - ay);
    float wsw = (1.0f - ax) * ay;
    float wse = ax * ay;

    size_t plane0 = (size_t)b * C * HW;
    size_t srcoff = plane0 + (size_t)h * W + w;
    int d00 = yf * W + xf;
    for (int c = 0; c < C; ++c) {
        float v = im0[srcoff + (size_t)c * HW];
        float* o = out + plane0 + (size_t)c * HW + d00;
        atomicAdd(o,         v * wnw);
        atomicAdd(o + 1,     v * wne);
        atomicAdd(o + W,     v * wsw);
        atomicAdd(o + W + 1, v * wse);
    }
}

// ---------- Pass B: output-tile-owning workgroups, LDS accumulation ----------
__global__ __launch_bounds__(256) void warp_tile_kernel(
    const float* __restrict__ im0, const float* __restrict__ flow,
    float* __restrict__ out)
{
    __shared__ float acc[NCH][T][T];   // 64 KB

    const int tx0 = blockIdx.x * T;
    const int ty0 = blockIdx.y * T;
    const int bz  = blockIdx.z;            // b*NCG + chg
    const int b   = bz >> 2;               // NCG = 4
    const int c0  = (bz & 3) * NCH;
    const int tid = threadIdx.x;

    // zero LDS accumulator
    float* accf = &acc[0][0][0];
    #pragma unroll
    for (int i = 0; i < (NCH * T * T) / 256; ++i)
        accf[i * 256 + tid] = 0.0f;
    __syncthreads();

    const float* flowb = flow + (size_t)b * HW * 2;
    const float* im0b  = im0  + (size_t)b * C * HW + (size_t)c0 * HW;

    constexpr int ITERS = (WIN * WIN) / 256;   // 100
    for (int it = 0; it < ITERS; ++it) {
        int i  = it * 256 + tid;
        int ry = i / WIN;
        int rx = i - ry * WIN;
        int sy = ty0 - RAD + ry;
        int sx = tx0 - RAD + rx;

        float wnw = 0, wne = 0, wsw = 0, wse = 0;
        int lx = 0, ly = 0;
        bool p00 = false, p01 = false, p10 = false, p11 = false;
        bool any = false;

        if ((unsigned)sy < (unsigned)H && (unsigned)sx < (unsigned)W) {
            float2 f = reinterpret_cast<const float2*>(flowb)[sy * W + sx];
            if (fabsf(f.x) <= FR && fabsf(f.y) <= FR) {
                float xd = (float)sx + f.x;
                float yd = (float)sy + f.y;
                float xff = floorf(xd), yff = floorf(yd);
                int xf = (int)xff, yf = (int)yff;
                if (xf >= 0 && yf >= 0 && xf + 1 < W && yf + 1 < H) {
                    float ax = xd - xff, ay = yd - yff;
                    wnw = (1.0f - ax) * (1.0f - ay);
                    wne = ax * (1.0f - ay);
                    wsw = (1.0f - ax) * ay;
                    wse = ax * ay;
                    lx = xf - tx0;
                    ly = yf - ty0;
                    p00 = (unsigned)ly       < (unsigned)T && (unsigned)lx       < (unsigned)T;
                    p01 = (unsigned)ly       < (unsigned)T && (unsigned)(lx + 1) < (unsigned)T;
                    p10 = (unsigned)(ly + 1) < (unsigned)T && (unsigned)lx       < (unsigned)T;
                    p11 = (unsigned)(ly + 1) < (unsigned)T && (unsigned)(lx + 1) < (unsigned)T;
                    any = p00 | p01 | p10 | p11;
                }
            }
        }

        if (any) {
            int soff = sy * W + sx;
            #pragma unroll
            for (int c = 0; c < NCH; ++c) {
                float v = im0b[(size_t)c * HW + soff];
                if (p00) atomicAdd(&acc[c][ly][lx],         v * wnw);
                if (p01) atomicAdd(&acc[c][ly][lx + 1],     v * wne);
                if (p10) atomicAdd(&acc[c][ly + 1][lx],     v * wsw);
                if (p11) atomicAdd(&acc[c][ly + 1][lx + 1], v * wse);
            }
        }
    }
    __syncthreads();

    // flush: out += acc (exclusive tile ownership -> plain RMW, coalesced float4)
    float* outb = out + (size_t)b * C * HW + (size_t)c0 * HW
                      + (size_t)ty0 * W + tx0;
    constexpr int Q = T / 4;                    // float4s per row = 16
    constexpr int FL = NCH * T * Q;             // total float4s = 4096
    for (int i = tid; i < FL; i += 256) {
        int c   = i / (T * Q);
        int rem = i - c * (T * Q);
        int y   = rem / Q;
        int x4  = rem - y * Q;
        float4 a = *reinterpret_cast<float4*>(&acc[c][y][x4 * 4]);
        float4* o = reinterpret_cast<float4*>(outb + (size_t)c * HW + (size_t)y * W + x4 * 4);
        float4 cur = *o;
        cur.x += a.x; cur.y += a.y; cur.z += a.z; cur.w += a.w;
        *o = cur;
    }
}

extern "C" void kernel_launch(void* const* d_in, const int* in_sizes, int n_in,
                              void* d_out, int out_size, void* d_ws, size_t ws_size,
                              hipStream_t stream) {
    const float* im0  = (const float*)d_in[0];
    const float* flow = (const float*)d_in[1];
    float* out = (float*)d_out;

    // harness poisons d_out; zero it every call
    hipMemsetAsync(out, 0, (size_t)out_size * sizeof(float), stream);

    // Pass A: rare far-fliers (global atomics onto zeroed out)
    constexpr int total = B * H * W;
    warp_far_kernel<<<(total + 255) / 256, 256, 0, stream>>>(im0, flow, out);

    // Pass B: tiled bulk (ordered after A on the stream; exclusive-tile plain RMW)
    dim3 grid(W / T, H / T, B * NCG);   // 8 x 8 x 16 = 1024 workgroups
    warp_tile_kernel<<<grid, 256, 0, stream>>>(im0, flow, out);
}